// Round 2
// baseline (415.220 us; speedup 1.0000x reference)
//
#include <hip/hip_runtime.h>
#include <hip/hip_bf16.h>
#include <stdint.h>

// Problem dims (fixed by reference setup_inputs)
#define Mdim 8192   // B*S = 4*2048
#define Ndim 4096   // OUT
#define Kdim 4096   // IN

// GEMM tile geometry: 256x256 tile, K-slice = 64, ring-of-3 slice buffers.
#define BM 256
#define BN 256
#define NSLICE (Kdim / 64)   // 64 K-slices

typedef int v4i __attribute__((ext_vector_type(4)));

__device__ __forceinline__ void gload_lds16(const void* g, void* l) {
  __builtin_amdgcn_global_load_lds(
      (const __attribute__((address_space(1))) unsigned int*)g,
      (__attribute__((address_space(3))) unsigned int*)l,
      16 /*bytes*/, 0 /*offset*/, 0 /*aux*/);
}

// ---------------------------------------------------------------------------
// Kernel 1: quantize activations. xi = clip(rint((x*input_scale)*(1/act)))
// ---------------------------------------------------------------------------
__global__ void quant_x_kernel(const float* __restrict__ x,
                               const float* __restrict__ in_scale,
                               const float* __restrict__ act_scale_p,
                               int8_t* __restrict__ xq) {
  const float inv_act = 1.0f / (*act_scale_p);
  const int64_t tid = (int64_t)blockIdx.x * blockDim.x + threadIdx.x;
  const int64_t base = tid * 16;
  const int k0 = (int)(base & (Kdim - 1));  // Kdim is pow2
  const float4* xv = (const float4*)(x + base);
  const float4* sv = (const float4*)(in_scale + k0);
  alignas(16) int8_t ob[16];
#pragma unroll
  for (int j = 0; j < 4; ++j) {
    float4 xx = xv[j];
    float4 ss = sv[j];
    float r0 = rintf((xx.x * ss.x) * inv_act);
    float r1 = rintf((xx.y * ss.y) * inv_act);
    float r2 = rintf((xx.z * ss.z) * inv_act);
    float r3 = rintf((xx.w * ss.w) * inv_act);
    r0 = fminf(fmaxf(r0, -127.f), 127.f);
    r1 = fminf(fmaxf(r1, -127.f), 127.f);
    r2 = fminf(fmaxf(r2, -127.f), 127.f);
    r3 = fminf(fmaxf(r3, -127.f), 127.f);
    ob[j * 4 + 0] = (int8_t)r0;
    ob[j * 4 + 1] = (int8_t)r1;
    ob[j * 4 + 2] = (int8_t)r2;
    ob[j * 4 + 3] = (int8_t)r3;
  }
  *(v4i*)(xq + base) = *(const v4i*)ob;
}

// ---------------------------------------------------------------------------
// Kernel 2: pack int32 weights to int8 ([N,K] row-major kept as-is = B^T).
// ---------------------------------------------------------------------------
__global__ void pack_w_kernel(const int* __restrict__ w, int8_t* __restrict__ wq) {
  const int64_t tid = (int64_t)blockIdx.x * blockDim.x + threadIdx.x;
  const int64_t base = tid * 16;
  const int4* wv = (const int4*)(w + base);
  alignas(16) int8_t ob[16];
#pragma unroll
  for (int j = 0; j < 4; ++j) {
    int4 t = wv[j];
    ob[j * 4 + 0] = (int8_t)t.x;
    ob[j * 4 + 1] = (int8_t)t.y;
    ob[j * 4 + 2] = (int8_t)t.z;
    ob[j * 4 + 3] = (int8_t)t.w;
  }
  *(v4i*)(wq + base) = *(const v4i*)ob;
}

// ---------------------------------------------------------------------------
// Kernel 3: int8 GEMM. C[M,N] = Aq[M,K] . Bq[N,K]^T
//
// Ring-of-3 K-slice schedule (de-lockstepped): 96 KiB LDS = 3 x (A 16K + B 16K)
// slice buffers. ONE barrier + ONE counted VMCNT(4) per K-slice; within a
// slice waves free-run so ds_read (LDS pipe) of one wave overlaps MFMA
// (matrix pipe) of another — the cross-wave overlap the previous 8-barrier
// lockstep structure suppressed. Prefetch distance = 2 slices (~2800 cyc >>
// 900-cyc HBM latency). Swizzled layout unchanged (0 bank conflicts):
// 64B rows, phys_chunk = logical ^ ((row>>1)&3), applied to the GLOBAL
// source address (global_load_lds dest stays linear).
//
// Race audit: slice s ready <= per-wave VMCNT(4) precedes the barrier, so
// barrier release implies ALL waves' slice-s DMAs landed. Overwrite of
// buf[s%3] (by slice s+3 STGs) happens after the end-of-s barrier, by which
// point all reads of buf[s%3] were serviced (compiler lgkmcnt before the
// consuming MFMAs precedes barrier arrival). Tail wrap prefetch writes only
// dead buffers; VMCNT(0) drains before endpgm.
// ---------------------------------------------------------------------------
#define PBAR()                        \
  do {                                \
    asm volatile("" ::: "memory");    \
    __builtin_amdgcn_s_barrier();     \
    asm volatile("" ::: "memory");    \
  } while (0)
#define VMCNT(n) asm volatile("s_waitcnt vmcnt(" #n ")" ::: "memory")

__global__ __launch_bounds__(512, 2) void gemm_i8_kernel(
    const int8_t* __restrict__ Aq, const int8_t* __restrict__ Bq,
    const float* __restrict__ w_scale, const float* __restrict__ bias,
    const float* __restrict__ act_scale_p, float* __restrict__ out) {
  __shared__ alignas(16) int8_t As[3][BM * 64];  // 3 x 16 KiB
  __shared__ alignas(16) int8_t Bs[3][BN * 64];  // 3 x 16 KiB

  const int t = threadIdx.x;

  // Grid 512 = 32 m-blocks x 16 n-blocks; 2-wide m supertile for B reuse.
  const int lin = blockIdx.x;
  const int within = lin & 31;
  const int m_blk = (lin >> 5) * 2 + (within & 1);  // 0..31
  const int n_blk = within >> 1;                    // 0..15
  const int m0 = m_blk * BM;
  const int n0 = n_blk * BN;

  // Staging: thread t fills LDS slot t*16 (row = t>>2 in half h, phys chunk
  // = (t&3) ^ ((row>>1)&3) applied to the GLOBAL source address).
  const int srow = t >> 2;                            // 0..127
  const int scol = ((t & 3) ^ ((t >> 3) & 3)) * 16;   // swizzled k-offset
  const int8_t* gA0 = Aq + (int64_t)(m0 + srow) * Kdim + scol;  // rows 0-127
  const int8_t* gA1 = gA0 + (int64_t)128 * Kdim;                // rows 128-255
  const int8_t* gB0 = Bq + (int64_t)(n0 + srow) * Kdim + scol;
  const int8_t* gB1 = gB0 + (int64_t)128 * Kdim;
  const int ldst = t * 16;

  const int w = t >> 6;           // wave 0..7
  const int l = t & 63;           // lane
  const int wm = (w >> 2) * 128;  // wave C-rows origin within tile (2M)
  const int wn = (w & 3) * 64;    // wave C-cols origin within tile (4N)
  const int lrow = l & 15;        // fragment row (m for A, n for B)
  const int lk = ((l >> 4) ^ ((l >> 1) & 3)) * 16;  // swizzled phys chunk
  const int abase = (wm + lrow) * 64 + lk;
  const int bbase = (wn + lrow) * 64 + lk;

  v4i acc[8][4] = {};

#define STG_SLICE(s, r)                              \
  do {                                               \
    const int ko_ = (s) * 64;                        \
    gload_lds16(gA0 + ko_, &As[r][ldst]);            \
    gload_lds16(gA1 + ko_, &As[r][8192 + ldst]);     \
    gload_lds16(gB0 + ko_, &Bs[r][ldst]);            \
    gload_lds16(gB1 + ko_, &Bs[r][8192 + ldst]);     \
  } while (0)

  // Prologue: stage slices 0 and 1 (8 loads), wait for slice 0's 4.
  STG_SLICE(0, 0);
  STG_SLICE(1, 1);
  VMCNT(4);
  PBAR();

  int ring = 0;  // s % 3
  for (int s = 0; s < NSLICE; ++s) {
    const int r = ring;
    int rn = ring + 2; if (rn >= 3) rn -= 3;       // (s+2) % 3
    int sp = s + 2; if (sp >= NSLICE) sp -= NSLICE; // dummy wrap at tail
    const int ko = sp * 64;

    const int8_t* Ab = As[r];
    const int8_t* Bb = Bs[r];
    v4i af[4], bf[4];

    // ---- sub-phase 0: mh=0 ----
#pragma unroll
    for (int j = 0; j < 4; ++j) bf[j] = *(const v4i*)&Bb[bbase + j * 1024];
#pragma unroll
    for (int i = 0; i < 4; ++i) af[i] = *(const v4i*)&Ab[abase + i * 1024];
    // prefetch slice s+2: A halves
    gload_lds16(gA0 + ko, &As[rn][ldst]);
    gload_lds16(gA1 + ko, &As[rn][8192 + ldst]);
    __builtin_amdgcn_s_setprio(1);
#pragma unroll
    for (int i = 0; i < 4; ++i)
#pragma unroll
      for (int j = 0; j < 4; ++j)
        acc[i][j] = __builtin_amdgcn_mfma_i32_16x16x64_i8(af[i], bf[j], acc[i][j], 0, 0, 0);
    __builtin_amdgcn_s_setprio(0);

    // ---- sub-phase 1: mh=1 ----
#pragma unroll
    for (int i = 0; i < 4; ++i) af[i] = *(const v4i*)&Ab[abase + 4096 + i * 1024];
    // prefetch slice s+2: B halves
    gload_lds16(gB0 + ko, &Bs[rn][ldst]);
    gload_lds16(gB1 + ko, &Bs[rn][8192 + ldst]);
    __builtin_amdgcn_s_setprio(1);
#pragma unroll
    for (int i = 0; i < 4; ++i)
#pragma unroll
      for (int j = 0; j < 4; ++j)
        acc[4 + i][j] = __builtin_amdgcn_mfma_i32_16x16x64_i8(af[i], bf[j], acc[4 + i][j], 0, 0, 0);
    __builtin_amdgcn_s_setprio(0);

    VMCNT(4);  // slice s+1's 4 loads landed; s+2's 4 stay in flight
    PBAR();    // all waves' slice s+1 data visible; skew bounded to 1 slice

    ring = ring + 1; if (ring >= 3) ring -= 3;
  }
  VMCNT(0);  // drain tail dummy prefetches

  // Epilogue: D mapping col = lane&15, row = (lane>>4)*4 + reg
  const float act = *act_scale_p;
  const int rowbase = (l >> 4) * 4;
#pragma unroll
  for (int j = 0; j < 4; ++j) {
    const int n = n0 + wn + j * 16 + lrow;
    const float sc = act * w_scale[n];
    const float bs = bias[n];
#pragma unroll
    for (int i = 0; i < 8; ++i) {
      const int mb = m0 + wm + i * 16 + rowbase;
#pragma unroll
      for (int r = 0; r < 4; ++r) {
        out[(int64_t)(mb + r) * Ndim + n] = (float)acc[i][j][r] * sc + bs;
      }
    }
  }
}

// ---------------------------------------------------------------------------
extern "C" void kernel_launch(void* const* d_in, const int* in_sizes, int n_in,
                              void* d_out, int out_size, void* d_ws, size_t ws_size,
                              hipStream_t stream) {
  const float* x        = (const float*)d_in[0];
  const float* in_scale = (const float*)d_in[1];
  const float* actp     = (const float*)d_in[2];
  const int*   w_int    = (const int*)d_in[3];
  const float* w_scale  = (const float*)d_in[4];
  const float* bias     = (const float*)d_in[5];
  float* out = (float*)d_out;

  int8_t* Aq = (int8_t*)d_ws;                        // 32 MiB
  int8_t* Bq = (int8_t*)d_ws + (size_t)Mdim * Kdim;  // 16 MiB

  {
    const int64_t nthreads = (int64_t)Mdim * Kdim / 16;  // 2,097,152
    quant_x_kernel<<<(int)(nthreads / 256), 256, 0, stream>>>(x, in_scale, actp, Aq);
  }
  {
    const int64_t nthreads = (int64_t)Ndim * Kdim / 16;  // 1,048,576
    pack_w_kernel<<<(int)(nthreads / 256), 256, 0, stream>>>(w_int, Bq);
  }
  {
    gemm_i8_kernel<<<dim3(512), 512, 0, stream>>>(Aq, Bq, w_scale, bias, actp, out);
  }
}

// Round 3
// 415.080 us; speedup vs baseline: 1.0003x; 1.0003x over previous
//
#include <hip/hip_runtime.h>
#include <hip/hip_bf16.h>
#include <stdint.h>

// Problem dims (fixed by reference setup_inputs)
#define Mdim 8192   // B*S = 4*2048
#define Ndim 4096   // OUT
#define Kdim 4096   // IN

// GEMM tile geometry: 256x256 tile, BK=128 (two K=64 slices), 8 waves.
#define BM 256
#define BN 256
#define BK 128

typedef int v4i __attribute__((ext_vector_type(4)));

__device__ __forceinline__ void gload_lds16(const void* g, void* l) {
  __builtin_amdgcn_global_load_lds(
      (const __attribute__((address_space(1))) unsigned int*)g,
      (__attribute__((address_space(3))) unsigned int*)l,
      16 /*bytes*/, 0 /*offset*/, 0 /*aux*/);
}

// ---------------------------------------------------------------------------
// Kernel 1: quantize activations. xi = clip(rint((x*input_scale)*(1/act)))
// ---------------------------------------------------------------------------
__global__ void quant_x_kernel(const float* __restrict__ x,
                               const float* __restrict__ in_scale,
                               const float* __restrict__ act_scale_p,
                               int8_t* __restrict__ xq) {
  const float inv_act = 1.0f / (*act_scale_p);
  const int64_t tid = (int64_t)blockIdx.x * blockDim.x + threadIdx.x;
  const int64_t base = tid * 16;
  const int k0 = (int)(base & (Kdim - 1));  // Kdim is pow2
  const float4* xv = (const float4*)(x + base);
  const float4* sv = (const float4*)(in_scale + k0);
  alignas(16) int8_t ob[16];
#pragma unroll
  for (int j = 0; j < 4; ++j) {
    float4 xx = xv[j];
    float4 ss = sv[j];
    float r0 = rintf((xx.x * ss.x) * inv_act);
    float r1 = rintf((xx.y * ss.y) * inv_act);
    float r2 = rintf((xx.z * ss.z) * inv_act);
    float r3 = rintf((xx.w * ss.w) * inv_act);
    r0 = fminf(fmaxf(r0, -127.f), 127.f);
    r1 = fminf(fmaxf(r1, -127.f), 127.f);
    r2 = fminf(fmaxf(r2, -127.f), 127.f);
    r3 = fminf(fmaxf(r3, -127.f), 127.f);
    ob[j * 4 + 0] = (int8_t)r0;
    ob[j * 4 + 1] = (int8_t)r1;
    ob[j * 4 + 2] = (int8_t)r2;
    ob[j * 4 + 3] = (int8_t)r3;
  }
  *(v4i*)(xq + base) = *(const v4i*)ob;
}

// ---------------------------------------------------------------------------
// Kernel 2: pack int32 weights to int8 ([N,K] row-major kept as-is = B^T).
// ---------------------------------------------------------------------------
__global__ void pack_w_kernel(const int* __restrict__ w, int8_t* __restrict__ wq) {
  const int64_t tid = (int64_t)blockIdx.x * blockDim.x + threadIdx.x;
  const int64_t base = tid * 16;
  const int4* wv = (const int4*)(w + base);
  alignas(16) int8_t ob[16];
#pragma unroll
  for (int j = 0; j < 4; ++j) {
    int4 t = wv[j];
    ob[j * 4 + 0] = (int8_t)t.x;
    ob[j * 4 + 1] = (int8_t)t.y;
    ob[j * 4 + 2] = (int8_t)t.z;
    ob[j * 4 + 3] = (int8_t)t.w;
  }
  *(v4i*)(wq + base) = *(const v4i*)ob;
}

// ---------------------------------------------------------------------------
// Kernel 3: int8 GEMM, 256^2 8-phase schedule. C[M,N] = Aq[M,K] . Bq[N,K]^T
//
// Round-1 verified structure (512 thr = 8 waves 2Mx4N; 2 barriers/phase;
// counted VMCNT(4) at phases 1&3 only; XOR-swizzled 64B-row LDS via
// pre-swizzled global source; 0 bank conflicts), with two deltas:
//
// (F) NO lgkmcnt(0) drain before MFMA. Round-1's phase = 653 cyc MFMA +
//     576 cyc LDS drain SERIALIZED (measured 1360 cyc/phase) because the
//     explicit drain parked every wave until its whole read queue emptied.
//     The pre-MFMA barrier is now a raw s_barrier (no memory clobber) and
//     the backend emits fine-grained counted lgkmcnt(N) per fragment, so
//     MFMA issue overlaps the LDS drain. Release barriers (end of phase)
//     keep the memory-pinned form; VMCNT placement unchanged, so the
//     all-waves-drained-before-read invariant is identical to round-1.
//
// (A) XCD-chunked block remap (T1): work = (hw&7)*64 + hw>>3 (bijective,
//     512%8==0). Each XCD owns a contiguous 4-m-band x all-n region; its
//     32 concurrent CUs share 2 MB of A-panels -> L2-resident A, uniform
//     L3 B -> shorter load service -> shorter VMCNT waits.
// ---------------------------------------------------------------------------
#define PBAR()                        \
  do {                                \
    asm volatile("" ::: "memory");    \
    __builtin_amdgcn_s_barrier();     \
    asm volatile("" ::: "memory");    \
  } while (0)
#define VMCNT(n) asm volatile("s_waitcnt vmcnt(" #n ")" ::: "memory")

#define MFMA16(mh)                                                        \
  do {                                                                    \
    __builtin_amdgcn_s_setprio(1);                                        \
    _Pragma("unroll") for (int i = 0; i < 4; ++i) {                       \
      _Pragma("unroll") for (int j = 0; j < 4; ++j) {                     \
        acc[(mh) * 4 + i][j] = __builtin_amdgcn_mfma_i32_16x16x64_i8(     \
            af[i], bf[j], acc[(mh) * 4 + i][j], 0, 0, 0);                 \
      }                                                                   \
    }                                                                     \
    __builtin_amdgcn_s_setprio(0);                                        \
  } while (0)

__global__ __launch_bounds__(512, 2) void gemm_i8_kernel(
    const int8_t* __restrict__ Aq, const int8_t* __restrict__ Bq,
    const float* __restrict__ w_scale, const float* __restrict__ bias,
    const float* __restrict__ act_scale_p, float* __restrict__ out) {
  __shared__ alignas(16) int8_t As[2][2][BM * 64];  // [buf][kslice] 4x16KB
  __shared__ alignas(16) int8_t Bs[2][2][BN * 64];

  const int t = threadIdx.x;

  // (A) XCD-aware remap, then 2-wide m supertile decode (grid 32m x 16n).
  const int hw = blockIdx.x;
  const int lin = (hw & 7) * 64 + (hw >> 3);        // bijective: 512 % 8 == 0
  const int within = lin & 31;
  const int m_blk = (lin >> 5) * 2 + (within & 1);  // 0..31
  const int n_blk = within >> 1;                    // 0..15
  const int m0 = m_blk * BM;
  const int n0 = n_blk * BN;

  // Staging: thread t fills LDS slot t*16 (row = t>>2 in half h, phys chunk
  // = (t&3) ^ ((row>>1)&3) applied to the GLOBAL source address).
  const int srow = t >> 2;                            // 0..127
  const int scol = ((t & 3) ^ ((t >> 3) & 3)) * 16;   // swizzled k-offset
  const int8_t* gA0 = Aq + (int64_t)(m0 + srow) * Kdim + scol;  // rows 0-127
  const int8_t* gA1 = gA0 + (int64_t)128 * Kdim;                // rows 128-255
  const int8_t* gB0 = Bq + (int64_t)(n0 + srow) * Kdim + scol;
  const int8_t* gB1 = gB0 + (int64_t)128 * Kdim;
  const int ldst = t * 16;

  const int w = t >> 6;           // wave 0..7
  const int l = t & 63;           // lane
  const int wm = (w >> 2) * 128;  // wave C-rows origin within tile (2M)
  const int wn = (w & 3) * 64;    // wave C-cols origin within tile (4N)
  const int lrow = l & 15;        // fragment row (m for A, n for B)
  const int lk = ((l >> 4) ^ ((l >> 1) & 3)) * 16;  // swizzled phys chunk
  const int abase = (wm + lrow) * 64 + lk;
  const int bbase = (wn + lrow) * 64 + lk;

  v4i acc[8][4] = {};

#define STG(MAT, buf, ks, h, koff) \
  gload_lds16(g##MAT##h + (koff) + (ks) * 64, &MAT##s[buf][ks][(h) * 8192 + ldst])

  // Prologue: stage tile 0 into buf 0 (order: ks0 h0, ks0 h1, ks1 h0, ks1 h1)
  STG(A, 0, 0, 0, 0); STG(B, 0, 0, 0, 0);
  STG(A, 0, 0, 1, 0); STG(B, 0, 0, 1, 0);
  STG(A, 0, 1, 0, 0); STG(B, 0, 1, 0, 0);
  STG(A, 0, 1, 1, 0); STG(B, 0, 1, 1, 0);
  VMCNT(4);  // k-slice 0 landed; slice 1's 4 loads stay in flight
  PBAR();

  for (int kt = 0; kt < Kdim; kt += BK) {
    const int cur = (kt >> 7) & 1;
    const int nxt = cur ^ 1;
    int kn = kt + BK;
    if (kn >= Kdim) kn = 0;  // dummy wrap: keeps vmcnt counts uniform

    v4i af[4], bf[4];

    // ---- phase 0: ks=0, mh=0 ----
#pragma unroll
    for (int j = 0; j < 4; ++j) bf[j] = *(const v4i*)&Bs[cur][0][bbase + j * 1024];
#pragma unroll
    for (int i = 0; i < 4; ++i) af[i] = *(const v4i*)&As[cur][0][abase + i * 1024];
    STG(A, nxt, 0, 0, kn); STG(B, nxt, 0, 0, kn);
    __builtin_amdgcn_s_barrier();  // raw: backend emits counted lgkm waits
    MFMA16(0);
    PBAR();

    // ---- phase 1: ks=0, mh=1 ----
#pragma unroll
    for (int i = 0; i < 4; ++i) af[i] = *(const v4i*)&As[cur][0][abase + 4096 + i * 1024];
    STG(A, nxt, 0, 1, kn); STG(B, nxt, 0, 1, kn);
    __builtin_amdgcn_s_barrier();
    MFMA16(1);
    VMCNT(4);  // drain this tile's k-slice 1; 4 prefetch loads in flight
    PBAR();

    // ---- phase 2: ks=1, mh=0 ----
#pragma unroll
    for (int j = 0; j < 4; ++j) bf[j] = *(const v4i*)&Bs[cur][1][bbase + j * 1024];
#pragma unroll
    for (int i = 0; i < 4; ++i) af[i] = *(const v4i*)&As[cur][1][abase + i * 1024];
    STG(A, nxt, 1, 0, kn); STG(B, nxt, 1, 0, kn);
    __builtin_amdgcn_s_barrier();
    MFMA16(0);
    PBAR();

    // ---- phase 3: ks=1, mh=1 ----
#pragma unroll
    for (int i = 0; i < 4; ++i) af[i] = *(const v4i*)&As[cur][1][abase + 4096 + i * 1024];
    STG(A, nxt, 1, 1, kn); STG(B, nxt, 1, 1, kn);
    __builtin_amdgcn_s_barrier();
    MFMA16(1);
    VMCNT(4);  // drain next tile's k-slice 0; its slice 1 stays in flight
    PBAR();
  }
  VMCNT(0);  // drain dummy prefetch before LDS teardown

  // Epilogue: D mapping col = lane&15, row = (lane>>4)*4 + reg
  const float act = *act_scale_p;
  const int rowbase = (l >> 4) * 4;
#pragma unroll
  for (int j = 0; j < 4; ++j) {
    const int n = n0 + wn + j * 16 + lrow;
    const float sc = act * w_scale[n];
    const float bs = bias[n];
#pragma unroll
    for (int i = 0; i < 8; ++i) {
      const int mb = m0 + wm + i * 16 + rowbase;
#pragma unroll
      for (int r = 0; r < 4; ++r) {
        out[(int64_t)(mb + r) * Ndim + n] = (float)acc[i][j][r] * sc + bs;
      }
    }
  }
}

// ---------------------------------------------------------------------------
extern "C" void kernel_launch(void* const* d_in, const int* in_sizes, int n_in,
                              void* d_out, int out_size, void* d_ws, size_t ws_size,
                              hipStream_t stream) {
  const float* x        = (const float*)d_in[0];
  const float* in_scale = (const float*)d_in[1];
  const float* actp     = (const float*)d_in[2];
  const int*   w_int    = (const int*)d_in[3];
  const float* w_scale  = (const float*)d_in[4];
  const float* bias     = (const float*)d_in[5];
  float* out = (float*)d_out;

  int8_t* Aq = (int8_t*)d_ws;                        // 32 MiB
  int8_t* Bq = (int8_t*)d_ws + (size_t)Mdim * Kdim;  // 16 MiB

  {
    const int64_t nthreads = (int64_t)Mdim * Kdim / 16;  // 2,097,152
    quant_x_kernel<<<(int)(nthreads / 256), 256, 0, stream>>>(x, in_scale, actp, Aq);
  }
  {
    const int64_t nthreads = (int64_t)Ndim * Kdim / 16;  // 1,048,576
    pack_w_kernel<<<(int)(nthreads / 256), 256, 0, stream>>>(w_int, Bq);
  }
  {
    gemm_i8_kernel<<<dim3(512), 512, 0, stream>>>(Aq, Bq, w_scale, bias, actp, out);
  }
}

// Round 4
// 404.876 us; speedup vs baseline: 1.0255x; 1.0252x over previous
//
#include <hip/hip_runtime.h>
#include <hip/hip_bf16.h>
#include <stdint.h>

// Problem dims (fixed by reference setup_inputs)
#define Mdim 8192   // B*S = 4*2048
#define Ndim 4096   // OUT
#define Kdim 4096   // IN

// GEMM tile geometry: 256x256 tile, BK=128 (two K=64 slices), 8 waves.
#define BM 256
#define BN 256
#define BK 128

typedef int v4i __attribute__((ext_vector_type(4)));

__device__ __forceinline__ void gload_lds16(const void* g, void* l) {
  __builtin_amdgcn_global_load_lds(
      (const __attribute__((address_space(1))) unsigned int*)g,
      (__attribute__((address_space(3))) unsigned int*)l,
      16 /*bytes*/, 0 /*offset*/, 0 /*aux*/);
}

// ---------------------------------------------------------------------------
// Kernel 1: quantize activations. xi = clip(rint((x*input_scale)*(1/act)))
// ---------------------------------------------------------------------------
__global__ void quant_x_kernel(const float* __restrict__ x,
                               const float* __restrict__ in_scale,
                               const float* __restrict__ act_scale_p,
                               int8_t* __restrict__ xq) {
  const float inv_act = 1.0f / (*act_scale_p);
  const int64_t tid = (int64_t)blockIdx.x * blockDim.x + threadIdx.x;
  const int64_t base = tid * 16;
  const int k0 = (int)(base & (Kdim - 1));  // Kdim is pow2
  const float4* xv = (const float4*)(x + base);
  const float4* sv = (const float4*)(in_scale + k0);
  alignas(16) int8_t ob[16];
#pragma unroll
  for (int j = 0; j < 4; ++j) {
    float4 xx = xv[j];
    float4 ss = sv[j];
    float r0 = rintf((xx.x * ss.x) * inv_act);
    float r1 = rintf((xx.y * ss.y) * inv_act);
    float r2 = rintf((xx.z * ss.z) * inv_act);
    float r3 = rintf((xx.w * ss.w) * inv_act);
    r0 = fminf(fmaxf(r0, -127.f), 127.f);
    r1 = fminf(fmaxf(r1, -127.f), 127.f);
    r2 = fminf(fmaxf(r2, -127.f), 127.f);
    r3 = fminf(fmaxf(r3, -127.f), 127.f);
    ob[j * 4 + 0] = (int8_t)r0;
    ob[j * 4 + 1] = (int8_t)r1;
    ob[j * 4 + 2] = (int8_t)r2;
    ob[j * 4 + 3] = (int8_t)r3;
  }
  *(v4i*)(xq + base) = *(const v4i*)ob;
}

// ---------------------------------------------------------------------------
// Kernel 2: pack int32 weights to int8 ([N,K] row-major kept as-is = B^T).
// ---------------------------------------------------------------------------
__global__ void pack_w_kernel(const int* __restrict__ w, int8_t* __restrict__ wq) {
  const int64_t tid = (int64_t)blockIdx.x * blockDim.x + threadIdx.x;
  const int64_t base = tid * 16;
  const int4* wv = (const int4*)(w + base);
  alignas(16) int8_t ob[16];
#pragma unroll
  for (int j = 0; j < 4; ++j) {
    int4 t = wv[j];
    ob[j * 4 + 0] = (int8_t)t.x;
    ob[j * 4 + 1] = (int8_t)t.y;
    ob[j * 4 + 2] = (int8_t)t.z;
    ob[j * 4 + 3] = (int8_t)t.w;
  }
  *(v4i*)(wq + base) = *(const v4i*)ob;
}

// ---------------------------------------------------------------------------
// Kernel 3: int8 GEMM, 256^2 8-phase schedule. C[M,N] = Aq[M,K] . Bq[N,K]^T
//
// Round-1 verified structure (512 thr = 8 waves 2Mx4N; default blockIdx
// mapping — round-3's XCD remap REVERTED, it ballooned FETCH 101->153 MB by
// putting all 16 B-panels in each XCD's 4MB L2; 2-wide m supertile restored;
// counted VMCNT(4) at phases 1&3 only; XOR-swizzled 64B-row LDS via
// pre-swizzled global source; 0 bank conflicts). ONE delta vs round 1:
//
// (F) NO lgkmcnt(0) drain before MFMA. Round-1's phase = 653 cyc MFMA +
//     ~770 cyc LDS traffic SERIALIZED (measured ~1360 cyc/phase): the
//     explicit clobbered drain parked every wave until the CU-wide read
//     queue emptied. Pre-MFMA barrier is now a RAW s_barrier (no clobber,
//     no drain); the backend emits per-fragment counted lgkmcnt(N), so
//     wave w's MFMAs begin as soon as ITS fragments land while the LDS
//     pipe still services other waves (cross-wave skew within the phase).
//     Correctness: each phase's ds_reads are ordered after the previous
//     phase-end PBAR/VMCNT (both carry "memory" clobbers) which is what
//     guarantees DMA visibility; the pre-MFMA barrier is pure rhythm.
// ---------------------------------------------------------------------------
#define PBAR()                        \
  do {                                \
    asm volatile("" ::: "memory");    \
    __builtin_amdgcn_s_barrier();     \
    asm volatile("" ::: "memory");    \
  } while (0)
#define VMCNT(n) asm volatile("s_waitcnt vmcnt(" #n ")" ::: "memory")

#define MFMA16(mh)                                                        \
  do {                                                                    \
    __builtin_amdgcn_s_setprio(1);                                        \
    _Pragma("unroll") for (int i = 0; i < 4; ++i) {                       \
      _Pragma("unroll") for (int j = 0; j < 4; ++j) {                     \
        acc[(mh) * 4 + i][j] = __builtin_amdgcn_mfma_i32_16x16x64_i8(     \
            af[i], bf[j], acc[(mh) * 4 + i][j], 0, 0, 0);                 \
      }                                                                   \
    }                                                                     \
    __builtin_amdgcn_s_setprio(0);                                        \
  } while (0)

__global__ __launch_bounds__(512, 2) void gemm_i8_kernel(
    const int8_t* __restrict__ Aq, const int8_t* __restrict__ Bq,
    const float* __restrict__ w_scale, const float* __restrict__ bias,
    const float* __restrict__ act_scale_p, float* __restrict__ out) {
  __shared__ alignas(16) int8_t As[2][2][BM * 64];  // [buf][kslice] 4x16KB
  __shared__ alignas(16) int8_t Bs[2][2][BN * 64];

  const int t = threadIdx.x;

  // Grid 512 = 32 m-blocks x 16 n-blocks; 2-wide m supertile for B reuse.
  // (Default blockIdx order: per-XCD working set = few B panels, L2-resident.)
  const int lin = blockIdx.x;
  const int within = lin & 31;
  const int m_blk = (lin >> 5) * 2 + (within & 1);  // 0..31
  const int n_blk = within >> 1;                    // 0..15
  const int m0 = m_blk * BM;
  const int n0 = n_blk * BN;

  // Staging: thread t fills LDS slot t*16 (row = t>>2 in half h, phys chunk
  // = (t&3) ^ ((row>>1)&3) applied to the GLOBAL source address).
  const int srow = t >> 2;                            // 0..127
  const int scol = ((t & 3) ^ ((t >> 3) & 3)) * 16;   // swizzled k-offset
  const int8_t* gA0 = Aq + (int64_t)(m0 + srow) * Kdim + scol;  // rows 0-127
  const int8_t* gA1 = gA0 + (int64_t)128 * Kdim;                // rows 128-255
  const int8_t* gB0 = Bq + (int64_t)(n0 + srow) * Kdim + scol;
  const int8_t* gB1 = gB0 + (int64_t)128 * Kdim;
  const int ldst = t * 16;

  const int w = t >> 6;           // wave 0..7
  const int l = t & 63;           // lane
  const int wm = (w >> 2) * 128;  // wave C-rows origin within tile (2M)
  const int wn = (w & 3) * 64;    // wave C-cols origin within tile (4N)
  const int lrow = l & 15;        // fragment row (m for A, n for B)
  const int lk = ((l >> 4) ^ ((l >> 1) & 3)) * 16;  // swizzled phys chunk
  const int abase = (wm + lrow) * 64 + lk;
  const int bbase = (wn + lrow) * 64 + lk;

  v4i acc[8][4] = {};

#define STG(MAT, buf, ks, h, koff) \
  gload_lds16(g##MAT##h + (koff) + (ks) * 64, &MAT##s[buf][ks][(h) * 8192 + ldst])

  // Prologue: stage tile 0 into buf 0 (order: ks0 h0, ks0 h1, ks1 h0, ks1 h1)
  STG(A, 0, 0, 0, 0); STG(B, 0, 0, 0, 0);
  STG(A, 0, 0, 1, 0); STG(B, 0, 0, 1, 0);
  STG(A, 0, 1, 0, 0); STG(B, 0, 1, 0, 0);
  STG(A, 0, 1, 1, 0); STG(B, 0, 1, 1, 0);
  VMCNT(4);  // k-slice 0 landed; slice 1's 4 loads stay in flight
  PBAR();

  for (int kt = 0; kt < Kdim; kt += BK) {
    const int cur = (kt >> 7) & 1;
    const int nxt = cur ^ 1;
    int kn = kt + BK;
    if (kn >= Kdim) kn = 0;  // dummy wrap: keeps vmcnt counts uniform

    v4i af[4], bf[4];

    // ---- phase 0: ks=0, mh=0 ----
#pragma unroll
    for (int j = 0; j < 4; ++j) bf[j] = *(const v4i*)&Bs[cur][0][bbase + j * 1024];
#pragma unroll
    for (int i = 0; i < 4; ++i) af[i] = *(const v4i*)&As[cur][0][abase + i * 1024];
    STG(A, nxt, 0, 0, kn); STG(B, nxt, 0, 0, kn);
    __builtin_amdgcn_s_barrier();  // raw: backend emits counted lgkm waits
    MFMA16(0);
    PBAR();

    // ---- phase 1: ks=0, mh=1 ----
#pragma unroll
    for (int i = 0; i < 4; ++i) af[i] = *(const v4i*)&As[cur][0][abase + 4096 + i * 1024];
    STG(A, nxt, 0, 1, kn); STG(B, nxt, 0, 1, kn);
    __builtin_amdgcn_s_barrier();
    MFMA16(1);
    VMCNT(4);  // drain this tile's k-slice 1; 4 prefetch loads in flight
    PBAR();

    // ---- phase 2: ks=1, mh=0 ----
#pragma unroll
    for (int j = 0; j < 4; ++j) bf[j] = *(const v4i*)&Bs[cur][1][bbase + j * 1024];
#pragma unroll
    for (int i = 0; i < 4; ++i) af[i] = *(const v4i*)&As[cur][1][abase + i * 1024];
    STG(A, nxt, 1, 0, kn); STG(B, nxt, 1, 0, kn);
    __builtin_amdgcn_s_barrier();
    MFMA16(0);
    PBAR();

    // ---- phase 3: ks=1, mh=1 ----
#pragma unroll
    for (int i = 0; i < 4; ++i) af[i] = *(const v4i*)&As[cur][1][abase + 4096 + i * 1024];
    STG(A, nxt, 1, 1, kn); STG(B, nxt, 1, 1, kn);
    __builtin_amdgcn_s_barrier();
    MFMA16(1);
    VMCNT(4);  // drain next tile's k-slice 0; its slice 1 stays in flight
    PBAR();
  }
  VMCNT(0);  // drain dummy prefetch before LDS teardown

  // Epilogue: D mapping col = lane&15, row = (lane>>4)*4 + reg
  const float act = *act_scale_p;
  const int rowbase = (l >> 4) * 4;
#pragma unroll
  for (int j = 0; j < 4; ++j) {
    const int n = n0 + wn + j * 16 + lrow;
    const float sc = act * w_scale[n];
    const float bs = bias[n];
#pragma unroll
    for (int i = 0; i < 8; ++i) {
      const int mb = m0 + wm + i * 16 + rowbase;
#pragma unroll
      for (int r = 0; r < 4; ++r) {
        out[(int64_t)(mb + r) * Ndim + n] = (float)acc[i][j][r] * sc + bs;
      }
    }
  }
}

// ---------------------------------------------------------------------------
extern "C" void kernel_launch(void* const* d_in, const int* in_sizes, int n_in,
                              void* d_out, int out_size, void* d_ws, size_t ws_size,
                              hipStream_t stream) {
  const float* x        = (const float*)d_in[0];
  const float* in_scale = (const float*)d_in[1];
  const float* actp     = (const float*)d_in[2];
  const int*   w_int    = (const int*)d_in[3];
  const float* w_scale  = (const float*)d_in[4];
  const float* bias     = (const float*)d_in[5];
  float* out = (float*)d_out;

  int8_t* Aq = (int8_t*)d_ws;                        // 32 MiB
  int8_t* Bq = (int8_t*)d_ws + (size_t)Mdim * Kdim;  // 16 MiB

  {
    const int64_t nthreads = (int64_t)Mdim * Kdim / 16;  // 2,097,152
    quant_x_kernel<<<(int)(nthreads / 256), 256, 0, stream>>>(x, in_scale, actp, Aq);
  }
  {
    const int64_t nthreads = (int64_t)Ndim * Kdim / 16;  // 1,048,576
    pack_w_kernel<<<(int)(nthreads / 256), 256, 0, stream>>>(w_int, Bq);
  }
  {
    gemm_i8_kernel<<<dim3(512), 512, 0, stream>>>(Aq, Bq, w_scale, bias, actp, out);
  }
}